// Round 5
// baseline (112.331 us; speedup 1.0000x reference)
//
#include <hip/hip_runtime.h>

// out[b,p,ch] = mask[ch] ? x[b, perm[ch,p], ch] : x[b,p,ch]
// B=32, HW=3136, C=256, fp32. Compulsory traffic ~206 MB -> ~33 us roofline.
#define HW      3136
#define NCH     256
#define THREADS 1024
#define SLOTS   4      // ceil(HW/1024); slot 3 valid only for t < 64
#define TAIL    64     // HW - 3*THREADS

// v5: one block per CU (grid 256). Block = 32 channels x HW, as 4 units of
// 8ch. Two 50KB LDS buffers; software pipeline overlaps next-unit global
// reads with current-unit gather+stores (macro T14). Stores deferred per
// unit-PAIR so one thread writes a full 64B line (4x dwordx4) -- no
// cross-block write-combining dependence (v3's 1.5x write amplification).
// XCD map: cb32 = bid&7 -> each XCD owns one 32ch slab for all batches
// (perm slice 400KB shared by its 32 CUs in L2; x/out lines disjoint).
__global__ __launch_bounds__(THREADS) void jumble_v5_kernel(
    const float* __restrict__ x, const float* __restrict__ mask,
    const int* __restrict__ perm, float* __restrict__ out) {
  __shared__ float bufA[4 * HW];  // 50,176 B
  __shared__ float bufB[4 * HW];  // 50,176 B

  const unsigned bid = blockIdx.x;
  const unsigned cb32 = bid & 7u;  // channel slab == XCD (bid % 8)
  const unsigned b = bid >> 3;     // batch
  const unsigned chb = cb32 * 32u;
  const unsigned t = threadIdx.x;

  const float* __restrict__ xb = x + (size_t)b * (HW * NCH);
  float* __restrict__ ob = out + (size_t)b * (HW * NCH);

  float4 lo[SLOTS] = {}, hi[SLOTS] = {};    // current unit x data
  float4 nlo[SLOTS] = {}, nhi[SLOTS] = {};  // prefetched next unit
  float4 e_lo[SLOTS], e_hi[SLOTS];          // gathered even unit (8ch)
  float4 o_lo[SLOTS], o_hi[SLOTS];          // gathered odd unit (8ch)

#define VALID(j) ((j) < 3 || t < TAIL)
#define PIX(j) (t + (unsigned)(j)*THREADS)

// issue all lo loads first, then hi: stage(lo) can start with hi in flight
#define LOAD_UNIT(dlo, dhi, ch0)                               \
  {                                                            \
    const float4* src = (const float4*)(xb + (ch0));           \
    _Pragma("unroll") for (int j = 0; j < SLOTS; ++j) {        \
      if (VALID(j)) dlo[j] = src[(size_t)PIX(j) * (NCH / 4)];  \
    }                                                          \
    _Pragma("unroll") for (int j = 0; j < SLOTS; ++j) {        \
      if (VALID(j)) dhi[j] = src[(size_t)PIX(j) * (NCH / 4) + 1]; \
    }                                                          \
  }

// channel-major LDS: bank = p%32 on writes (2-way, free), r%32 on gathers
#define STAGE(buf, v)                                          \
  {                                                            \
    _Pragma("unroll") for (int j = 0; j < SLOTS; ++j) {        \
      if (VALID(j)) {                                          \
        const unsigned p = PIX(j);                             \
        buf[0 * HW + p] = v[j].x;                              \
        buf[1 * HW + p] = v[j].y;                              \
        buf[2 * HW + p] = v[j].z;                              \
        buf[3 * HW + p] = v[j].w;                              \
      }                                                        \
    }                                                          \
  }

#define GATHER4(buf, c0, res)                                      \
  {                                                                \
    const int* __restrict__ pr0 = perm + (size_t)((c0) + 0) * HW;  \
    const int* __restrict__ pr1 = perm + (size_t)((c0) + 1) * HW;  \
    const int* __restrict__ pr2 = perm + (size_t)((c0) + 2) * HW;  \
    const int* __restrict__ pr3 = perm + (size_t)((c0) + 3) * HW;  \
    const bool m0 = mask[(c0) + 0] != 0.0f;                        \
    const bool m1 = mask[(c0) + 1] != 0.0f;                        \
    const bool m2 = mask[(c0) + 2] != 0.0f;                        \
    const bool m3 = mask[(c0) + 3] != 0.0f;                        \
    _Pragma("unroll") for (int j = 0; j < SLOTS; ++j) {            \
      if (VALID(j)) {                                              \
        const int p = (int)PIX(j);                                 \
        const int r0 = m0 ? pr0[p] : p;                            \
        const int r1 = m1 ? pr1[p] : p;                            \
        const int r2 = m2 ? pr2[p] : p;                            \
        const int r3 = m3 ? pr3[p] : p;                            \
        res[j].x = buf[0 * HW + r0];                               \
        res[j].y = buf[1 * HW + r1];                               \
        res[j].z = buf[2 * HW + r2];                               \
        res[j].w = buf[3 * HW + r3];                               \
      }                                                            \
    }                                                              \
  }

// full 64B line per thread: 4 back-to-back dwordx4
#define STORE16(chp)                                                 \
  {                                                                  \
    _Pragma("unroll") for (int j = 0; j < SLOTS; ++j) {              \
      if (VALID(j)) {                                                \
        float4* dst = (float4*)(ob + (size_t)PIX(j) * NCH + (chp));  \
        dst[0] = e_lo[j];                                            \
        dst[1] = e_hi[j];                                            \
        dst[2] = o_lo[j];                                            \
        dst[3] = o_hi[j];                                            \
      }                                                              \
    }                                                                \
  }

#define ROTATE()                                   \
  {                                                \
    _Pragma("unroll") for (int j = 0; j < SLOTS; ++j) { \
      lo[j] = nlo[j];                              \
      hi[j] = nhi[j];                              \
    }                                              \
  }

  LOAD_UNIT(lo, hi, chb + 0u)

  // ---- unit 0 (even) ----
  STAGE(bufA, lo)
  __syncthreads();
  LOAD_UNIT(nlo, nhi, chb + 8u)  // prefetch unit 1; drains under gathers
  GATHER4(bufA, chb + 0u, e_lo)
  STAGE(bufB, hi)
  __syncthreads();
  GATHER4(bufB, chb + 4u, e_hi)

  // ---- unit 1 (odd) ----
  ROTATE()
  STAGE(bufA, lo)  // bufA free: last read before prev sync
  __syncthreads();
  LOAD_UNIT(nlo, nhi, chb + 16u)
  GATHER4(bufA, chb + 8u, o_lo)
  STAGE(bufB, hi)
  __syncthreads();
  GATHER4(bufB, chb + 12u, o_hi)
  STORE16(chb + 0u)  // ch chb..chb+15, full lines

  // ---- unit 2 (even) ----
  ROTATE()
  STAGE(bufA, lo)
  __syncthreads();
  LOAD_UNIT(nlo, nhi, chb + 24u)
  GATHER4(bufA, chb + 16u, e_lo)
  STAGE(bufB, hi)
  __syncthreads();
  GATHER4(bufB, chb + 20u, e_hi)

  // ---- unit 3 (odd) ----
  ROTATE()
  STAGE(bufA, lo)
  __syncthreads();
  GATHER4(bufA, chb + 24u, o_lo)
  STAGE(bufB, hi)
  __syncthreads();
  GATHER4(bufB, chb + 28u, o_hi)
  STORE16(chb + 16u)
}

extern "C" void kernel_launch(void* const* d_in, const int* in_sizes, int n_in,
                              void* d_out, int out_size, void* d_ws, size_t ws_size,
                              hipStream_t stream) {
  const float* x = (const float*)d_in[0];
  const float* mask = (const float*)d_in[1];
  const int* perm = (const int*)d_in[2];
  float* out = (float*)d_out;

  jumble_v5_kernel<<<256, THREADS, 0, stream>>>(x, mask, perm, out);
}

// Round 6
// 44.163 us; speedup vs baseline: 2.5436x; 2.5436x over previous
//
#include <hip/hip_runtime.h>

// out[b,p,ch] = mask[ch] ? x[b, perm[ch,p], ch] : x[b,p,ch]
// B=32, HW=3136, C=256, fp32. Compulsory ~206 MB -> ~25-33 us roofline.
#define HW      3136
#define NCH     256
#define LDP     (HW + 1)   // padded channel stride: 3137 % 32 == 1 -> bank=(c+r)%32
#define THREADS 1024

// stage: 2*HW float4s per step = 6272 -> 7 slots, slot 6 valid t<128
#define SSLOT 7
#define STAIL 128
// gather: HW pixels / 256 groups = 12.25 -> 13 slots, slot 12 valid t<256
#define GSLOT 13
#define GTAIL 256

// v6 = v2's proven memory shapes + T14 async-STAGE pipeline over 4 batches.
// Block = (8-channel slab, 4 batches); grid 256 = 32 chblk x 8 batch-quads,
// 1 block/CU (LDS 100 KB). Steady state: issue x-loads(batch k+1) -> regs,
// gather+store(batch k) [hides the load latency], barrier, regs -> LDS,
// barrier. perm indices loaded ONCE, packed 2x16b in regs, reused 4 batches.
// XCD map: xcd owns chblks 4x..4x+3 = contiguous 32 ch = full 128B lines of
// x/out within one XCD; its 400 KB perm slice is L2-resident.
__global__ __launch_bounds__(THREADS) void jumble_v6_kernel(
    const float* __restrict__ x, const float* __restrict__ mask,
    const int* __restrict__ perm, float* __restrict__ out) {
  __shared__ float lds[8 * LDP];  // 100,384 B -> 1 block/CU, 16 waves

  const unsigned bid = blockIdx.x;
  const unsigned xcd = bid & 7u;
  const unsigned i = bid >> 3;                   // 0..31
  const unsigned chblk = xcd * 4u + (i & 3u);    // 0..31, 4 per XCD
  const unsigned b0 = (i >> 2) * 4u;             // batch quad
  const unsigned ch0 = chblk * 8u;
  const unsigned t = threadIdx.x;

  // gather thread org (v2 shape): 4-lane groups own one pixel, 2ch per lane
  const unsigned cp = t & 3u;
  const unsigned c0l = 2u * cp;
  const unsigned gp0 = t >> 2;

// ---- stage issue: paired lanes -> 32B chunks, 32 lines/wave (v2 shape) ----
#define ISSUE(pf, bb)                                                      \
  {                                                                        \
    const float4* __restrict__ src =                                       \
        (const float4*)(x + (size_t)(bb) * (HW * NCH)) + (ch0 / 4);        \
    _Pragma("unroll") for (int j = 0; j < SSLOT; ++j) {                    \
      const unsigned f = t + (unsigned)j * THREADS;                        \
      if (j < SSLOT - 1 || t < STAIL)                                      \
        pf[j] = src[(size_t)(f >> 1) * (NCH / 4) + (f & 1u)];              \
    }                                                                      \
  }

// ---- regs -> LDS, channel-major padded: bank=(c+p)%32, 2-way, free ----
#define DSWRITE(pf)                                                        \
  {                                                                        \
    _Pragma("unroll") for (int j = 0; j < SSLOT; ++j) {                    \
      const unsigned f = t + (unsigned)j * THREADS;                        \
      if (j < SSLOT - 1 || t < STAIL) {                                    \
        const unsigned p = f >> 1, cb = (f & 1u) * 4u;                     \
        lds[(cb + 0) * LDP + p] = pf[j].x;                                 \
        lds[(cb + 1) * LDP + p] = pf[j].y;                                 \
        lds[(cb + 2) * LDP + p] = pf[j].z;                                 \
        lds[(cb + 3) * LDP + p] = pf[j].w;                                 \
      }                                                                    \
    }                                                                      \
  }

// ---- gather from LDS + 32B-chunk stores (4-lane groups; v2 shape) ----
#define GATHER(bb)                                                         \
  {                                                                        \
    float* __restrict__ ob = out + (size_t)(bb) * (HW * NCH) + ch0;        \
    _Pragma("unroll") for (int k = 0; k < GSLOT; ++k) {                    \
      if (k < GSLOT - 1 || t < GTAIL) {                                    \
        const unsigned p = gp0 + (unsigned)k * 256u;                       \
        const unsigned rA = ridx[k] & 0xffffu;                             \
        const unsigned rB = ridx[k] >> 16;                                 \
        float2 v;                                                          \
        v.x = lds[(c0l + 0) * LDP + rA];                                   \
        v.y = lds[(c0l + 1) * LDP + rB];                                   \
        ((float2*)(ob + (size_t)p * NCH))[cp] = v;                         \
      }                                                                    \
    }                                                                      \
  }

  float4 pf[SSLOT];

  // prologue: x-loads for batch b0 in flight while perm indices load
  ISSUE(pf, b0 + 0)

  // ---- preload gather indices once (reused across all 4 batches) ----
  const int* __restrict__ prA = perm + (size_t)(ch0 + c0l) * HW;
  const int* __restrict__ prB = perm + (size_t)(ch0 + c0l + 1) * HW;
  const bool mA = mask[ch0 + c0l] != 0.0f;
  const bool mB = mask[ch0 + c0l + 1] != 0.0f;
  unsigned ridx[GSLOT];
#pragma unroll
  for (int k = 0; k < GSLOT; ++k) {
    if (k < GSLOT - 1 || t < GTAIL) {
      const int p = (int)(gp0 + (unsigned)k * 256u);
      const int rA = mA ? prA[p] : p;  // 64B-contiguous per 16-lane stream
      const int rB = mB ? prB[p] : p;
      ridx[k] = (unsigned)rA | ((unsigned)rB << 16);  // HW<4096 fits 16b
    }
  }

  DSWRITE(pf)  // compiler inserts counted vmcnt for pf
  __syncthreads();

  // ---- steady state: issue(k+1) || gather(k), then regs->LDS ----
  ISSUE(pf, b0 + 1)
  GATHER(b0 + 0)
  __syncthreads();  // all waves done reading LDS (drains vmcnt: pf ready)
  DSWRITE(pf)
  __syncthreads();

  ISSUE(pf, b0 + 2)
  GATHER(b0 + 1)
  __syncthreads();
  DSWRITE(pf)
  __syncthreads();

  ISSUE(pf, b0 + 3)
  GATHER(b0 + 2)
  __syncthreads();
  DSWRITE(pf)
  __syncthreads();

  GATHER(b0 + 3)
}

extern "C" void kernel_launch(void* const* d_in, const int* in_sizes, int n_in,
                              void* d_out, int out_size, void* d_ws, size_t ws_size,
                              hipStream_t stream) {
  const float* x = (const float*)d_in[0];
  const float* mask = (const float*)d_in[1];
  const int* perm = (const int*)d_in[2];
  float* out = (float*)d_out;

  jumble_v6_kernel<<<256, THREADS, 0, stream>>>(x, mask, perm, out);
}